// Round 15
// baseline (367.767 us; speedup 1.0000x reference)
//
#include <hip/hip_runtime.h>
#include <stdint.h>

#define T_TOK 2048
#define HDIM 1024
#define NEXP 8
#define IDIM 3584
#define MAXTILE 40

// ws layout (bytes)
#define WS_CNT   0
#define WS_BASE  64
#define WS_TE    128
#define WS_TM    384
#define WS_NT    640
#define WS_TOK   704
#define WS_GW    (WS_TOK + NEXP * T_TOK * 4)
#define WS_XB    (WS_GW + NEXP * T_TOK * 4)
#define WS_G     (WS_XB + T_TOK * HDIM * 2)
// g: 4096 pairs x IDIM bf16 = 29,360,128 B ; total ~33.7 MB

typedef __attribute__((ext_vector_type(8))) short bf16x8;
typedef __attribute__((ext_vector_type(16))) float f32x16;

__device__ __forceinline__ unsigned short f2bf(float f) {
    union { float f; unsigned int u; } a; a.f = f;
    unsigned int u = a.u;
    return (unsigned short)((u + 0x7fffu + ((u >> 16) & 1u)) >> 16);
}

__device__ __forceinline__ unsigned int cvt_pk_bf16(float lo, float hi) {
    unsigned int r;
    asm("v_cvt_pk_bf16_f32 %0, %1, %2" : "=v"(r) : "v"(lo), "v"(hi));
    return r;
}

__device__ __forceinline__ uint4 pack8(const float4 a, const float4 b) {
    uint4 r;
    r.x = cvt_pk_bf16(a.x, a.y);
    r.y = cvt_pk_bf16(a.z, a.w);
    r.z = cvt_pk_bf16(b.x, b.y);
    r.w = cvt_pk_bf16(b.z, b.w);
    return r;
}

__global__ __launch_bounds__(256) void xcvt_kernel(
    const float* __restrict__ x, unsigned short* __restrict__ xb)
{
    int i = (blockIdx.x * 256 + threadIdx.x) * 8;
    float4 a = *(const float4*)(x + i);
    float4 b = *(const float4*)(x + i + 4);
    *(uint4*)(xb + i) = pack8(a, b);
}

__global__ __launch_bounds__(256) void router_kernel(
    const float* __restrict__ x, const float* __restrict__ gate_w,
    int* __restrict__ cnt, int* __restrict__ tok, float* __restrict__ gw)
{
    int t = blockIdx.x * 4 + (threadIdx.x >> 6);
    int lane = threadIdx.x & 63;
    if (t >= T_TOK) return;
    const float* xr = x + (size_t)t * HDIM;
    float part[NEXP];
#pragma unroll
    for (int e = 0; e < NEXP; e++) part[e] = 0.f;
    for (int h = lane; h < HDIM; h += 64) {
        float xv = xr[h];
#pragma unroll
        for (int e = 0; e < NEXP; e++) part[e] += xv * gate_w[e * HDIM + h];
    }
#pragma unroll
    for (int e = 0; e < NEXP; e++) {
        float v = part[e];
#pragma unroll
        for (int o = 32; o > 0; o >>= 1) v += __shfl_xor(v, o);
        part[e] = v;
    }
    if (lane == 0) {
        int i0 = 0; float v0 = part[0];
#pragma unroll
        for (int e = 1; e < NEXP; e++) if (part[e] > v0) { v0 = part[e]; i0 = e; }
        int i1 = -1; float v1 = -3.4e38f;
#pragma unroll
        for (int e = 0; e < NEXP; e++) if (e != i0 && part[e] > v1) { v1 = part[e]; i1 = e; }
        float d = __expf(v1 - v0);
        float w1v = d / (1.f + d);
        float w0v = 1.f - w1v;
        int p0 = atomicAdd(&cnt[i0], 1);
        tok[i0 * T_TOK + p0] = t; gw[i0 * T_TOK + p0] = w0v;
        int p1 = atomicAdd(&cnt[i1], 1);
        tok[i1 * T_TOK + p1] = t; gw[i1 * T_TOK + p1] = w1v;
    }
}

__global__ void scan_kernel(const int* __restrict__ cnt, int* __restrict__ base,
                            int* __restrict__ tileE, int* __restrict__ tileM,
                            int* __restrict__ ntot)
{
    if (threadIdx.x == 0) {
        int s = 0, nt = 0;
        for (int e = 0; e < NEXP; e++) {
            base[e] = s; s += cnt[e];
            for (int m0 = 0; m0 < cnt[e]; m0 += 128) {
                tileE[nt] = e; tileM[nt] = m0; nt++;
            }
        }
        *ntot = nt;
    }
}

// ---------------- ffn1: g = silu(x@w1^T) * (x@w3^T) --------------------
// Tile 128 tok x 64 i, BK=32, 4 waves (32 tok each). A (x) loaded
// global->register per lane (16B frags). Only weights go through LDS
// (2-buf, 16 KB total). Raw s_barrier with lgkmcnt(0) ONLY — no vmem
// drain at barriers; all vmem waits are compiler register-dep waits.
#define F1_MFMA(AF, RO)                                                        \
    _Pragma("unroll")                                                          \
    for (int s = 0; s < 2; s++) {                                              \
      bf16x8 b1a = *(const bf16x8*)(lds + (RO) + bfo[0][s]);                   \
      bf16x8 b1b = *(const bf16x8*)(lds + (RO) + bfo[1][s]);                   \
      bf16x8 b3a = *(const bf16x8*)(lds + 8192u + (RO) + bfo[0][s]);           \
      bf16x8 b3b = *(const bf16x8*)(lds + 8192u + (RO) + bfo[1][s]);           \
      acc1[0] = __builtin_amdgcn_mfma_f32_32x32x16_bf16(AF[s], b1a, acc1[0], 0, 0, 0); \
      acc1[1] = __builtin_amdgcn_mfma_f32_32x32x16_bf16(AF[s], b1b, acc1[1], 0, 0, 0); \
      acc3[0] = __builtin_amdgcn_mfma_f32_32x32x16_bf16(AF[s], b3a, acc3[0], 0, 0, 0); \
      acc3[1] = __builtin_amdgcn_mfma_f32_32x32x16_bf16(AF[s], b3b, acc3[1], 0, 0, 0); \
    }

#define F1_STEP(ST, AF, W1C, W3C)                                              \
  {                                                                            \
    F1_MFMA(AF, ((unsigned)((ST) & 1)) * 4096u)                                \
    const unsigned wo = ((unsigned)(((ST) + 1) & 1)) * 4096u;                  \
    *(uint4*)(lds + wo + wdst) = pack8(W1C[0], W1C[1]);                        \
    *(uint4*)(lds + 8192u + wo + wdst) = pack8(W3C[0], W3C[1]);                \
    const int ka = min(((ST) + 2) * 32, HDIM - 32);                            \
    AF[0] = *(const bf16x8*)(arow + ka);                                       \
    AF[1] = *(const bf16x8*)(arow + ka + 16);                                  \
    const int kw = min(((ST) + 3) * 32, HDIM - 32);                            \
    W1C[0] = *(const float4*)(w1e + kw);                                       \
    W1C[1] = *(const float4*)(w1e + kw + 4);                                   \
    W3C[0] = *(const float4*)(w3e + kw);                                       \
    W3C[1] = *(const float4*)(w3e + kw + 4);                                   \
    asm volatile("s_waitcnt lgkmcnt(0)" ::: "memory");                         \
    __builtin_amdgcn_sched_barrier(0);                                         \
    __builtin_amdgcn_s_barrier();                                              \
  }

__global__ __launch_bounds__(256, 3) void ffn1_mfma(
    const unsigned short* __restrict__ xb,
    const float* __restrict__ w1,
    const float* __restrict__ w3,
    const int* __restrict__ cnt, const int* __restrict__ base,
    const int* __restrict__ tok,
    const int* __restrict__ tileE, const int* __restrict__ tileM,
    const int* __restrict__ ntot,
    unsigned short* __restrict__ g)
{
    const int ti = blockIdx.y;
    if (ti >= *ntot) return;
    const int e = tileE[ti];
    const int m0 = tileM[ti];
    const int cntE = cnt[e];
    const int i0 = blockIdx.x * 64;
    const int tid = threadIdx.x;
    const int lane = tid & 63;
    const int wid = tid >> 6;

    __shared__ __align__(16) unsigned char lds[16384];
    // w1s buf0 @0, buf1 @4096 ; w3s buf0 @8192, buf1 @12288 (each 64x32 bf16)

    const int fr = lane & 31;
    const int hi = lane >> 5;

    // A row base (per lane): token row, 16B frags at k + s*16
    const unsigned short* arow;
    {
        int row = wid * 32 + fr;
        int t = tok[e * T_TOK + min(m0 + row, cntE - 1)];
        arow = xb + (size_t)t * HDIM + hi * 8;
    }

    // B-frag LDS read offsets: row = f2*32+fr (64B rows), slot swizzled
    unsigned bfo[2][2];
#pragma unroll
    for (int f2 = 0; f2 < 2; f2++)
#pragma unroll
        for (int s = 0; s < 2; s++) {
            unsigned row = (unsigned)(f2 * 32 + fr);
            unsigned slot = ((unsigned)(s * 2 + hi)) ^ ((row >> 1) & 3u);
            bfo[f2][s] = row * 64u + slot * 16u;
        }

    // weight staging: thread -> (row=tid>>2 of 64, c4=tid&3), 16B slot
    const int srow = tid >> 2;
    const int c4 = tid & 3;
    const unsigned wdst = (unsigned)srow * 64u +
                          (((unsigned)c4 ^ (((unsigned)srow >> 1) & 3u)) * 16u);
    const float* w1e = w1 + ((size_t)e * IDIM + i0 + srow) * HDIM + c4 * 8;
    const float* w3e = w3 + ((size_t)e * IDIM + i0 + srow) * HDIM + c4 * 8;

    f32x16 acc1[2], acc3[2];
#pragma unroll
    for (int a = 0; a < 2; a++)
#pragma unroll
        for (int r = 0; r < 16; r++) { acc1[a][r] = 0.f; acc3[a][r] = 0.f; }

    bf16x8 af0[2], af1[2];
    float4 w1cA[2], w3cA[2], w1cB[2], w3cB[2];

    // prologue: W(0) -> lds[0] via temps; load A(0),A(1), W(1),W(2)
    {
        float4 t0 = *(const float4*)(w1e);
        float4 t1 = *(const float4*)(w1e + 4);
        float4 t2 = *(const float4*)(w3e);
        float4 t3 = *(const float4*)(w3e + 4);
        *(uint4*)(lds + wdst) = pack8(t0, t1);
        *(uint4*)(lds + 8192u + wdst) = pack8(t2, t3);
    }
    af0[0] = *(const bf16x8*)(arow);
    af0[1] = *(const bf16x8*)(arow + 16);
    af1[0] = *(const bf16x8*)(arow + 32);
    af1[1] = *(const bf16x8*)(arow + 48);
    w1cA[0] = *(const float4*)(w1e + 32);  w1cA[1] = *(const float4*)(w1e + 36);
    w3cA[0] = *(const float4*)(w3e + 32);  w3cA[1] = *(const float4*)(w3e + 36);
    w1cB[0] = *(const float4*)(w1e + 64);  w1cB[1] = *(const float4*)(w1e + 68);
    w3cB[0] = *(const float4*)(w3e + 64);  w3cB[1] = *(const float4*)(w3e + 68);
    asm volatile("s_waitcnt lgkmcnt(0)" ::: "memory");
    __builtin_amdgcn_sched_barrier(0);
    __builtin_amdgcn_s_barrier();

#pragma unroll 1
    for (int dd = 0; dd < HDIM / 64; dd++) {
        F1_STEP(2 * dd,     af0, w1cA, w3cA);
        F1_STEP(2 * dd + 1, af1, w1cB, w3cB);
    }

    const int pbase = base[e] + m0;
    const int rb4 = 4 * hi;
#pragma unroll
    for (int f2 = 0; f2 < 2; f2++) {
#pragma unroll
        for (int r = 0; r < 16; r++) {
            int row = (r & 3) + 8 * (r >> 2) + rb4;
            int m = wid * 32 + row;
            if (m0 + m < cntE) {
                float h1 = acc1[f2][r], h3 = acc3[f2][r];
                float v = (h1 / (1.f + __expf(-h1))) * h3;
                g[(size_t)(pbase + m) * IDIM + i0 + f2 * 32 + fr] = f2bf(v);
            }
        }
    }
}

// ---------------- ffn2: out += gate * (g @ w2^T) -----------------------
// Tile 128 pairs x 64 h, BK=32, split-K x4 over IDIM. Same structure:
// g loaded global->reg per lane; only w2 via LDS (8 KB, 2-buf).
#define F2_STEP(ST, AF, W2C)                                                   \
  {                                                                            \
    const unsigned ro = ((unsigned)((ST) & 1)) * 4096u;                        \
    _Pragma("unroll")                                                          \
    for (int s = 0; s < 2; s++) {                                              \
      bf16x8 b0 = *(const bf16x8*)(lds + ro + bfo[0][s]);                      \
      bf16x8 b1 = *(const bf16x8*)(lds + ro + bfo[1][s]);                      \
      acc[0] = __builtin_amdgcn_mfma_f32_32x32x16_bf16(AF[s], b0, acc[0], 0, 0, 0); \
      acc[1] = __builtin_amdgcn_mfma_f32_32x32x16_bf16(AF[s], b1, acc[1], 0, 0, 0); \
    }                                                                          \
    const unsigned wo = ((unsigned)(((ST) + 1) & 1)) * 4096u;                  \
    *(uint4*)(lds + wo + wdst) = pack8(W2C[0], W2C[1]);                        \
    const int ka = min(((ST) + 2) * 32, KSP - 32);                             \
    AF[0] = *(const bf16x8*)(grow_p + ka);                                     \
    AF[1] = *(const bf16x8*)(grow_p + ka + 16);                                \
    const int kw = min(((ST) + 3) * 32, KSP - 32);                             \
    W2C[0] = *(const float4*)(w2e + kw);                                       \
    W2C[1] = *(const float4*)(w2e + kw + 4);                                   \
    asm volatile("s_waitcnt lgkmcnt(0)" ::: "memory");                         \
    __builtin_amdgcn_sched_barrier(0);                                         \
    __builtin_amdgcn_s_barrier();                                              \
  }

__global__ __launch_bounds__(256, 4) void ffn2_mfma(
    const unsigned short* __restrict__ g,
    const float* __restrict__ w2,
    const int* __restrict__ cnt, const int* __restrict__ base,
    const int* __restrict__ tok, const float* __restrict__ gw,
    const int* __restrict__ tileE, const int* __restrict__ tileM,
    const int* __restrict__ ntot,
    float* __restrict__ out)
{
    const int ti = blockIdx.y;
    if (ti >= *ntot) return;
    const int e = tileE[ti];
    const int m0 = tileM[ti];
    const int cntE = cnt[e];
    const int pane = blockIdx.x;               // 0..63
    const int h0 = (pane & 15) * 64;
    const int ks = pane >> 4;                  // 0..3
    const int tid = threadIdx.x;
    const int lane = tid & 63;
    const int wid = tid >> 6;

    __shared__ __align__(16) unsigned char lds[8192];
    // w2s buf0 @0, buf1 @4096 (each 64x32 bf16)

    const int KSP = IDIM / 4;                  // 896, 28 steps (even)
    const int kbeg = ks * KSP;

    const int fr = lane & 31;
    const int hi = lane >> 5;

    const unsigned short* grow_p;
    {
        int row = wid * 32 + fr;
        int gr = base[e] + min(m0 + row, cntE - 1);
        grow_p = g + (size_t)gr * IDIM + kbeg + hi * 8;
    }

    unsigned bfo[2][2];
#pragma unroll
    for (int f2 = 0; f2 < 2; f2++)
#pragma unroll
        for (int s = 0; s < 2; s++) {
            unsigned row = (unsigned)(f2 * 32 + fr);
            unsigned slot = ((unsigned)(s * 2 + hi)) ^ ((row >> 1) & 3u);
            bfo[f2][s] = row * 64u + slot * 16u;
        }

    const int srow = tid >> 2;
    const int c4 = tid & 3;
    const unsigned wdst = (unsigned)srow * 64u +
                          (((unsigned)c4 ^ (((unsigned)srow >> 1) & 3u)) * 16u);
    const float* w2e = w2 + ((size_t)e * HDIM + h0 + srow) * IDIM + kbeg + c4 * 8;

    f32x16 acc[2];
#pragma unroll
    for (int a = 0; a < 2; a++)
#pragma unroll
        for (int r = 0; r < 16; r++) acc[a][r] = 0.f;

    bf16x8 af0[2], af1[2];
    float4 w2cA[2], w2cB[2];

    {
        float4 t0 = *(const float4*)(w2e);
        float4 t1 = *(const float4*)(w2e + 4);
        *(uint4*)(lds + wdst) = pack8(t0, t1);
    }
    af0[0] = *(const bf16x8*)(grow_p);
    af0[1] = *(const bf16x8*)(grow_p + 16);
    af1[0] = *(const bf16x8*)(grow_p + 32);
    af1[1] = *(const bf16x8*)(grow_p + 48);
    w2cA[0] = *(const float4*)(w2e + 32);  w2cA[1] = *(const float4*)(w2e + 36);
    w2cB[0] = *(const float4*)(w2e + 64);  w2cB[1] = *(const float4*)(w2e + 68);
    asm volatile("s_waitcnt lgkmcnt(0)" ::: "memory");
    __builtin_amdgcn_sched_barrier(0);
    __builtin_amdgcn_s_barrier();

#pragma unroll 1
    for (int dd = 0; dd < (IDIM / 4) / 64; dd++) {   // 14 double-steps
        F2_STEP(2 * dd,     af0, w2cA);
        F2_STEP(2 * dd + 1, af1, w2cB);
    }

    const int rb4 = 4 * hi;
#pragma unroll
    for (int f2 = 0; f2 < 2; f2++) {
#pragma unroll
        for (int r = 0; r < 16; r++) {
            int row = (r & 3) + 8 * (r >> 2) + rb4;
            int m = wid * 32 + row;
            if (m0 + m < cntE) {
                int idx = e * T_TOK + m0 + m;
                int t = tok[idx];
                float wgt = gw[idx];
                atomicAdd(out + (size_t)t * HDIM + h0 + f2 * 32 + fr,
                          wgt * acc[f2][r]);
            }
        }
    }
}

extern "C" void kernel_launch(void* const* d_in, const int* in_sizes, int n_in,
                              void* d_out, int out_size, void* d_ws, size_t ws_size,
                              hipStream_t stream) {
    const float* x      = (const float*)d_in[0];
    const float* gate_w = (const float*)d_in[1];
    const float* w1     = (const float*)d_in[2];
    const float* w2     = (const float*)d_in[3];
    const float* w3     = (const float*)d_in[4];
    float* out = (float*)d_out;
    char* ws = (char*)d_ws;
    int* cnt   = (int*)(ws + WS_CNT);
    int* base  = (int*)(ws + WS_BASE);
    int* tileE = (int*)(ws + WS_TE);
    int* tileM = (int*)(ws + WS_TM);
    int* ntot  = (int*)(ws + WS_NT);
    int* tok   = (int*)(ws + WS_TOK);
    float* gw  = (float*)(ws + WS_GW);
    unsigned short* xb = (unsigned short*)(ws + WS_XB);
    unsigned short* g  = (unsigned short*)(ws + WS_G);

    hipMemsetAsync(cnt, 0, 64, stream);
    hipMemsetAsync(d_out, 0, (size_t)out_size * sizeof(float), stream);

    xcvt_kernel<<<T_TOK * HDIM / (256 * 8), 256, 0, stream>>>(x, xb);
    router_kernel<<<T_TOK / 4, 256, 0, stream>>>(x, gate_w, cnt, tok, gw);
    scan_kernel<<<1, 64, 0, stream>>>(cnt, base, tileE, tileM, ntot);
    ffn1_mfma<<<dim3(IDIM / 64, MAXTILE), 256, 0, stream>>>(xb, w1, w3, cnt, base, tok, tileE, tileM, ntot, g);
    ffn2_mfma<<<dim3(64, MAXTILE), 256, 0, stream>>>(g, w2, cnt, base, tok, gw, tileE, tileM, ntot, out);
}